// Round 1
// baseline (184.378 us; speedup 1.0000x reference)
//
#include <hip/hip_runtime.h>

// GSHashEncoding: out[i][c] = sum_k feats[i][k] * W[k][c]
//   feats[i][0..3] = codes[map0[i][d]][d]          (level-0 table, 65536 rows)
//   feats[i][4..7] = codes[65536 + map1[i][d]][d]  (level-1 table, 262144 rows)
// RESO = 2^21 rows, OUT_DIM = 48, all fp32, maps int32.
// Memory-bound on the 402 MB output write; stores are fully-coalesced float4.

#define RESO    2097152
#define OUT_DIM 48
#define LVL0    65536
#define BLK     256

__global__ __launch_bounds__(BLK) void gshash_kernel(
    const float* __restrict__ codes,
    const float* __restrict__ W,
    const int4*  __restrict__ map0,
    const int4*  __restrict__ map1,
    float*       __restrict__ out)
{
    __shared__ float Wl[8 * OUT_DIM];      // 1.5 KB
    __shared__ float feats[BLK * 9];       // padded stride 9 -> no bank conflicts

    const int t     = threadIdx.x;
    const int row_g = blockIdx.x * BLK + t;

    // Stage W (8x48 = 384 floats = 96 float4) into LDS.
    if (t < 96) {
        ((float4*)Wl)[t] = ((const float4*)W)[t];
    }

    // Phase 1: per-row feature gather.
    const int4 m0 = map0[row_g];           // coalesced 16B loads
    const int4 m1 = map1[row_g];
    const float* __restrict__ c1 = codes + LVL0 * 4;

    float f[8];
    f[0] = codes[m0.x * 4 + 0];
    f[1] = codes[m0.y * 4 + 1];
    f[2] = codes[m0.z * 4 + 2];
    f[3] = codes[m0.w * 4 + 3];
    f[4] = c1[m1.x * 4 + 0];
    f[5] = c1[m1.y * 4 + 1];
    f[6] = c1[m1.z * 4 + 2];
    f[7] = c1[m1.w * 4 + 3];

    #pragma unroll
    for (int k = 0; k < 8; ++k)
        feats[t * 9 + k] = f[k];           // stride 9: banks all distinct (2 lanes/bank = free)

    __syncthreads();

    // Phase 2: coalesced float4 output. Block tile = 256 rows * 48 cols = 12288 floats
    // = 3072 float4 = 12 iterations * 256 threads.
    float4* __restrict__ out4 = (float4*)(out + (size_t)blockIdx.x * (BLK * OUT_DIM));

    #pragma unroll
    for (int j = 0; j < 12; ++j) {
        const int e    = j * BLK + t;      // float4 index within tile
        const int row  = e / 12;           // 12 float4 per row
        const int col4 = (e - row * 12) * 4;

        const float* __restrict__ fp = &feats[row * 9];   // broadcast among 12 lanes
        float4 acc = make_float4(0.f, 0.f, 0.f, 0.f);
        #pragma unroll
        for (int k = 0; k < 8; ++k) {
            const float  fk = fp[k];
            const float4 w  = *(const float4*)&Wl[k * OUT_DIM + col4]; // 16B-aligned
            acc.x += fk * w.x;
            acc.y += fk * w.y;
            acc.z += fk * w.z;
            acc.w += fk * w.w;
        }
        out4[e] = acc;                     // lane t -> byte 16*t: perfectly coalesced
    }
}

extern "C" void kernel_launch(void* const* d_in, const int* in_sizes, int n_in,
                              void* d_out, int out_size, void* d_ws, size_t ws_size,
                              hipStream_t stream) {
    const float* codes = (const float*)d_in[0];
    const float* W     = (const float*)d_in[1];
    const int4*  map0  = (const int4*)d_in[2];   // (RESO,4) int32, 16B rows
    const int4*  map1  = (const int4*)d_in[3];
    float*       out   = (float*)d_out;

    const int grid = RESO / BLK;                 // 8192, exact
    gshash_kernel<<<grid, BLK, 0, stream>>>(codes, W, map0, map1, out);
}

// Round 3
// 177.011 us; speedup vs baseline: 1.0416x; 1.0416x over previous
//
#include <hip/hip_runtime.h>

// GSHashEncoding: out[i][c] = sum_k feats[i][k] * W[k][c]
//   feats[i][0..3] = codes[map0[i][d]][d]          (level-0 table, 65536x4)
//   feats[i][4..7] = codes[65536*4 + map1[i][d]*4 + d]  (level-1, 262144x4)
// RESO = 2^21 rows, OUT_DIM = 48 (= 12 float4), fp32.
//
// Structure: BLK=192 threads (3 waves), TILE=256 rows/block, grid=8192.
//  - Each thread owns a FIXED column group col4 = t%12 -> its 8x4 slice of W
//    lives in 32 VGPRs (no LDS W reads in the hot loop).
//  - Phase 1: gather 256 rows' 8 feats into LDS (stride 8, float4 writes).
//  - Phase 2: 16 iters; thread t handles row j*16 + t/12, cols [4*col4..+3].
//    Store index e = j*192 + t -> perfectly coalesced 16B/lane stores.
//  - Nontemporal stores + map loads (via clang ext_vector_type — the HIP
//    struct vector types are rejected by __builtin_nontemporal_*).

#define RESO    2097152
#define OUT_DIM 48
#define LVL0    65536
#define BLK     192
#define TILE    256
#define NITER   16            // TILE / (BLK/12)

typedef int   vi4 __attribute__((ext_vector_type(4)));
typedef float vf4 __attribute__((ext_vector_type(4)));

__global__ __launch_bounds__(BLK) void gshash_kernel(
    const float* __restrict__ codes,
    const float* __restrict__ W,
    const vi4*   __restrict__ map0,
    const vi4*   __restrict__ map1,
    float*       __restrict__ out)
{
    __shared__ float feats[TILE * 8];            // 8 KB, stride 8 (16B-aligned rows)

    const int t     = threadIdx.x;
    const int col4  = t % 12;                    // fixed float4 column group
    const int rbase = t / 12;                    // 0..15
    const size_t row0 = (size_t)blockIdx.x * TILE;

    // W slice -> 32 VGPRs (broadcast among the 16 threads sharing col4)
    vf4 Wv[8];
    #pragma unroll
    for (int k = 0; k < 8; ++k)
        Wv[k] = ((const vf4*)(W + k * OUT_DIM))[col4];

    // ---- Phase 1: gather TILE rows with BLK threads (rows t, and 192+t for t<64)
    const float* __restrict__ c1 = codes + LVL0 * 4;

    {
        const int r = t;                         // 0..191
        const vi4 m0 = __builtin_nontemporal_load(&map0[row0 + r]);
        const vi4 m1 = __builtin_nontemporal_load(&map1[row0 + r]);
        vf4 a, b;
        a.x = codes[m0.x * 4 + 0];
        a.y = codes[m0.y * 4 + 1];
        a.z = codes[m0.z * 4 + 2];
        a.w = codes[m0.w * 4 + 3];
        b.x = c1[m1.x * 4 + 0];
        b.y = c1[m1.y * 4 + 1];
        b.z = c1[m1.z * 4 + 2];
        b.w = c1[m1.w * 4 + 3];
        *(vf4*)&feats[r * 8]     = a;
        *(vf4*)&feats[r * 8 + 4] = b;
    }
    if (t < TILE - BLK) {                        // t < 64
        const int r = BLK + t;                   // 192..255
        const vi4 m0 = __builtin_nontemporal_load(&map0[row0 + r]);
        const vi4 m1 = __builtin_nontemporal_load(&map1[row0 + r]);
        vf4 a, b;
        a.x = codes[m0.x * 4 + 0];
        a.y = codes[m0.y * 4 + 1];
        a.z = codes[m0.z * 4 + 2];
        a.w = codes[m0.w * 4 + 3];
        b.x = c1[m1.x * 4 + 0];
        b.y = c1[m1.y * 4 + 1];
        b.z = c1[m1.z * 4 + 2];
        b.w = c1[m1.w * 4 + 3];
        *(vf4*)&feats[r * 8]     = a;
        *(vf4*)&feats[r * 8 + 4] = b;
    }

    __syncthreads();

    // ---- Phase 2: 16 coalesced float4 store waves
    vf4* __restrict__ out4 = (vf4*)(out + row0 * OUT_DIM);

    #pragma unroll
    for (int j = 0; j < NITER; ++j) {
        const int r = j * 16 + rbase;
        const vf4 fa = *(const vf4*)&feats[r * 8];      // 12-way broadcast
        const vf4 fb = *(const vf4*)&feats[r * 8 + 4];

        vf4 acc = fa.x * Wv[0];
        acc += fa.y * Wv[1];
        acc += fa.z * Wv[2];
        acc += fa.w * Wv[3];
        acc += fb.x * Wv[4];
        acc += fb.y * Wv[5];
        acc += fb.z * Wv[6];
        acc += fb.w * Wv[7];

        __builtin_nontemporal_store(acc, &out4[j * BLK + t]); // lane->16B contiguous
    }
}

extern "C" void kernel_launch(void* const* d_in, const int* in_sizes, int n_in,
                              void* d_out, int out_size, void* d_ws, size_t ws_size,
                              hipStream_t stream) {
    const float* codes = (const float*)d_in[0];
    const float* W     = (const float*)d_in[1];
    const vi4*   map0  = (const vi4*)d_in[2];
    const vi4*   map1  = (const vi4*)d_in[3];
    float*       out   = (float*)d_out;

    const int grid = RESO / TILE;                // 8192, exact
    gshash_kernel<<<grid, BLK, 0, stream>>>(codes, W, map0, map1, out);
}

// Round 4
// 164.797 us; speedup vs baseline: 1.1188x; 1.0741x over previous
//
#include <hip/hip_runtime.h>

// GSHashEncoding: out[i][c] = sum_k feats[i][k] * W[k][c]
//   feats[i][0..3] = codes[map0[i][d]][d]          (level-0 table, 65536x4)
//   feats[i][4..7] = codes[65536*4 + map1[i][d]*4+d] (level-1, 262144x4)
// RESO = 2^21 rows, OUT_DIM = 48 (12 float4), fp32 in/out, int32 maps.
//
// R4 theory: gather line-amplification (8 random 4B reads/row -> 8x 64B lines
// -> ~1.07 GB of line traffic) against a 5.25 MB fp32 table that does NOT fit
// the 4 MB per-XCD L2 under stream pollution -> served from L3, ~120 us.
// Fix: convert codes to bf16 (RNE) into d_ws each call -> 2.6 MB table is
// L2-resident everywhere; gathers become 2B loads. Compute stays fp32.
//
// Main kernel: BLK=192 (3 waves), TILE=256 rows, grid=8192.
//  - thread owns fixed col4=t%12; its 8x4 W slice lives in 32 VGPRs.
//  - phase 1 gathers 256 rows x 8 bf16 feats -> fp32 in LDS (stride 8).
//  - phase 2: 16 iters of perfectly-coalesced nontemporal float4 stores.

#define RESO    2097152
#define OUT_DIM 48
#define LVL0    65536
#define LVL1    262144
#define NCODES  (LVL0 + LVL1)          // 327680 rows x 4
#define BLK     192
#define TILE    256
#define NITER   16                     // TILE / (BLK/12)

typedef int            vi4 __attribute__((ext_vector_type(4)));
typedef float          vf4 __attribute__((ext_vector_type(4)));
typedef unsigned short vu4 __attribute__((ext_vector_type(4)));

static __device__ __forceinline__ unsigned short f2bf_rne(float x) {
    unsigned int u = __float_as_uint(x);
    u += 0x7fffu + ((u >> 16) & 1u);   // round-to-nearest-even (finite inputs)
    return (unsigned short)(u >> 16);
}
static __device__ __forceinline__ float bf2f(unsigned short h) {
    return __uint_as_float(((unsigned int)h) << 16);
}

// ---- prep: codes fp32 -> bf16 table in workspace (2.62 MB) ----
__global__ __launch_bounds__(256) void convert_kernel(
    const float* __restrict__ codes, unsigned short* __restrict__ bf)
{
    const int i = blockIdx.x * 256 + threadIdx.x;     // quad index, < NCODES
    const vf4 v = ((const vf4*)codes)[i];
    vu4 o;
    o.x = f2bf_rne(v.x); o.y = f2bf_rne(v.y);
    o.z = f2bf_rne(v.z); o.w = f2bf_rne(v.w);
    ((vu4*)bf)[i] = o;
}

// ---- main kernel (bf16 table variant) ----
__global__ __launch_bounds__(BLK) void gshash_bf16_kernel(
    const unsigned short* __restrict__ tab,   // bf16 codes, [327680][4]
    const float* __restrict__ W,
    const vi4*   __restrict__ map0,
    const vi4*   __restrict__ map1,
    float*       __restrict__ out)
{
    __shared__ float feats[TILE * 8];          // 8 KB

    const int t     = threadIdx.x;
    const int col4  = t % 12;
    const int rbase = t / 12;
    const size_t row0 = (size_t)blockIdx.x * TILE;

    vf4 Wv[8];
    #pragma unroll
    for (int k = 0; k < 8; ++k)
        Wv[k] = ((const vf4*)(W + k * OUT_DIM))[col4];

    const unsigned short* __restrict__ t1 = tab + LVL0 * 4;

    #pragma unroll
    for (int half = 0; half < 2; ++half) {
        const int r = half * BLK + t;
        if (half == 0 || t < TILE - BLK) {     // all threads, then t<64
            const vi4 m0 = __builtin_nontemporal_load(&map0[row0 + r]);
            const vi4 m1 = __builtin_nontemporal_load(&map1[row0 + r]);
            vf4 a, b;
            a.x = bf2f(tab[m0.x * 4 + 0]);
            a.y = bf2f(tab[m0.y * 4 + 1]);
            a.z = bf2f(tab[m0.z * 4 + 2]);
            a.w = bf2f(tab[m0.w * 4 + 3]);
            b.x = bf2f(t1[m1.x * 4 + 0]);
            b.y = bf2f(t1[m1.y * 4 + 1]);
            b.z = bf2f(t1[m1.z * 4 + 2]);
            b.w = bf2f(t1[m1.w * 4 + 3]);
            *(vf4*)&feats[r * 8]     = a;
            *(vf4*)&feats[r * 8 + 4] = b;
        }
    }

    __syncthreads();

    vf4* __restrict__ out4 = (vf4*)(out + row0 * OUT_DIM);

    #pragma unroll
    for (int j = 0; j < NITER; ++j) {
        const int r = j * 16 + rbase;
        const vf4 fa = *(const vf4*)&feats[r * 8];
        const vf4 fb = *(const vf4*)&feats[r * 8 + 4];

        vf4 acc = fa.x * Wv[0];
        acc += fa.y * Wv[1];
        acc += fa.z * Wv[2];
        acc += fa.w * Wv[3];
        acc += fb.x * Wv[4];
        acc += fb.y * Wv[5];
        acc += fb.z * Wv[6];
        acc += fb.w * Wv[7];

        __builtin_nontemporal_store(acc, &out4[j * BLK + t]);
    }
}

// ---- fallback (fp32 gather, R3 kernel) if ws too small ----
__global__ __launch_bounds__(BLK) void gshash_f32_kernel(
    const float* __restrict__ codes,
    const float* __restrict__ W,
    const vi4*   __restrict__ map0,
    const vi4*   __restrict__ map1,
    float*       __restrict__ out)
{
    __shared__ float feats[TILE * 8];
    const int t     = threadIdx.x;
    const int col4  = t % 12;
    const int rbase = t / 12;
    const size_t row0 = (size_t)blockIdx.x * TILE;

    vf4 Wv[8];
    #pragma unroll
    for (int k = 0; k < 8; ++k)
        Wv[k] = ((const vf4*)(W + k * OUT_DIM))[col4];

    const float* __restrict__ c1 = codes + LVL0 * 4;

    #pragma unroll
    for (int half = 0; half < 2; ++half) {
        const int r = half * BLK + t;
        if (half == 0 || t < TILE - BLK) {
            const vi4 m0 = __builtin_nontemporal_load(&map0[row0 + r]);
            const vi4 m1 = __builtin_nontemporal_load(&map1[row0 + r]);
            vf4 a, b;
            a.x = codes[m0.x * 4 + 0];
            a.y = codes[m0.y * 4 + 1];
            a.z = codes[m0.z * 4 + 2];
            a.w = codes[m0.w * 4 + 3];
            b.x = c1[m1.x * 4 + 0];
            b.y = c1[m1.y * 4 + 1];
            b.z = c1[m1.z * 4 + 2];
            b.w = c1[m1.w * 4 + 3];
            *(vf4*)&feats[r * 8]     = a;
            *(vf4*)&feats[r * 8 + 4] = b;
        }
    }
    __syncthreads();

    vf4* __restrict__ out4 = (vf4*)(out + row0 * OUT_DIM);
    #pragma unroll
    for (int j = 0; j < NITER; ++j) {
        const int r = j * 16 + rbase;
        const vf4 fa = *(const vf4*)&feats[r * 8];
        const vf4 fb = *(const vf4*)&feats[r * 8 + 4];
        vf4 acc = fa.x * Wv[0];
        acc += fa.y * Wv[1];
        acc += fa.z * Wv[2];
        acc += fa.w * Wv[3];
        acc += fb.x * Wv[4];
        acc += fb.y * Wv[5];
        acc += fb.z * Wv[6];
        acc += fb.w * Wv[7];
        __builtin_nontemporal_store(acc, &out4[j * BLK + t]);
    }
}

extern "C" void kernel_launch(void* const* d_in, const int* in_sizes, int n_in,
                              void* d_out, int out_size, void* d_ws, size_t ws_size,
                              hipStream_t stream) {
    const float* codes = (const float*)d_in[0];
    const float* W     = (const float*)d_in[1];
    const vi4*   map0  = (const vi4*)d_in[2];
    const vi4*   map1  = (const vi4*)d_in[3];
    float*       out   = (float*)d_out;

    const size_t tab_bytes = (size_t)NCODES * 4 * sizeof(unsigned short); // 2.62 MB
    const int    grid      = RESO / TILE;                                  // 8192

    if (ws_size >= tab_bytes) {
        unsigned short* tab = (unsigned short*)d_ws;
        convert_kernel<<<NCODES / 256, 256, 0, stream>>>(codes, tab);      // 1280 blocks
        gshash_bf16_kernel<<<grid, BLK, 0, stream>>>(tab, W, map0, map1, out);
    } else {
        gshash_f32_kernel<<<grid, BLK, 0, stream>>>(codes, W, map0, map1, out);
    }
}

// Round 5
// 164.293 us; speedup vs baseline: 1.1223x; 1.0031x over previous
//
#include <hip/hip_runtime.h>

// GSHashEncoding, R5: 3-kernel split to decouple irregular gather from streaming store.
//   k1 convert: codes fp32 -> bf16 table in ws (2.62 MB, L2-resident)
//   k2 gather : 4 rows/thread, 8x 2B table gathers/row -> packed ushort8 feats in ws (nt store)
//   k3 consume: coalesced feats read -> LDS -> W-in-VGPR matvec -> coalesced nt float4 stores
// out[i][c] = sum_k feats[i][k]*W[k][c]; RESO=2^21, OUT_DIM=48, fp32 out.

#define RESO    2097152
#define OUT_DIM 48
#define LVL0    65536
#define LVL1    262144
#define NCODES  (LVL0 + LVL1)
#define GBLK    256
#define GRPT    4                      // rows per thread in gather kernel
#define BLK     192                    // consumer block (3 waves)
#define TILE    256
#define NITER   16                     // TILE / (BLK/12)

typedef int            vi4 __attribute__((ext_vector_type(4)));
typedef float          vf4 __attribute__((ext_vector_type(4)));
typedef unsigned short vu4 __attribute__((ext_vector_type(4)));
typedef unsigned short vu8 __attribute__((ext_vector_type(8)));

static __device__ __forceinline__ unsigned short f2bf_rne(float x) {
    unsigned int u = __float_as_uint(x);
    u += 0x7fffu + ((u >> 16) & 1u);
    return (unsigned short)(u >> 16);
}
static __device__ __forceinline__ float bf2f(unsigned short h) {
    return __uint_as_float(((unsigned int)h) << 16);
}

// ---- k1: codes fp32 -> bf16 table ----
__global__ __launch_bounds__(256) void convert_kernel(
    const float* __restrict__ codes, unsigned short* __restrict__ bf)
{
    const int i = blockIdx.x * 256 + threadIdx.x;      // quad index < NCODES
    const vf4 v = ((const vf4*)codes)[i];
    vu4 o;
    o.x = f2bf_rne(v.x); o.y = f2bf_rne(v.y);
    o.z = f2bf_rne(v.z); o.w = f2bf_rne(v.w);
    ((vu4*)bf)[i] = o;
}

// ---- k2: pure gather. grid = RESO/(GBLK*GRPT) = 2048 ----
__global__ __launch_bounds__(GBLK) void gather_kernel(
    const unsigned short* __restrict__ tab,
    const vi4* __restrict__ map0,
    const vi4* __restrict__ map1,
    vu8*       __restrict__ feats16)
{
    const int t = threadIdx.x;
    const size_t base = (size_t)blockIdx.x * (GBLK * GRPT) + t;

    vi4 m0[GRPT], m1[GRPT];
    #pragma unroll
    for (int j = 0; j < GRPT; ++j) {
        m0[j] = __builtin_nontemporal_load(&map0[base + j * GBLK]);
        m1[j] = __builtin_nontemporal_load(&map1[base + j * GBLK]);
    }

    const unsigned short* __restrict__ t1 = tab + LVL0 * 4;

    #pragma unroll
    for (int j = 0; j < GRPT; ++j) {
        vu8 o;
        o[0] = tab[m0[j].x * 4 + 0];     // cached (table is the only cached stream)
        o[1] = tab[m0[j].y * 4 + 1];
        o[2] = tab[m0[j].z * 4 + 2];
        o[3] = tab[m0[j].w * 4 + 3];
        o[4] = t1[m1[j].x * 4 + 0];
        o[5] = t1[m1[j].y * 4 + 1];
        o[6] = t1[m1[j].z * 4 + 2];
        o[7] = t1[m1[j].w * 4 + 3];
        __builtin_nontemporal_store(o, &feats16[base + j * GBLK]);  // 16B/lane coalesced
    }
}

// ---- k3: streaming matvec + store. grid = RESO/TILE = 8192 ----
__global__ __launch_bounds__(BLK) void consume_kernel(
    const vu8*   __restrict__ feats16,
    const float* __restrict__ W,
    float*       __restrict__ out)
{
    __shared__ float feats[TILE * 8];          // 8 KB

    const int t     = threadIdx.x;
    const int col4  = t % 12;
    const int rbase = t / 12;
    const size_t row0 = (size_t)blockIdx.x * TILE;

    vf4 Wv[8];
    #pragma unroll
    for (int k = 0; k < 8; ++k)
        Wv[k] = ((const vf4*)(W + k * OUT_DIM))[col4];

    #pragma unroll
    for (int half = 0; half < 2; ++half) {
        const int r = half * BLK + t;
        if (half == 0 || t < TILE - BLK) {
            const vu8 v = __builtin_nontemporal_load(&feats16[row0 + r]);
            vf4 a, b;
            a.x = bf2f(v[0]); a.y = bf2f(v[1]); a.z = bf2f(v[2]); a.w = bf2f(v[3]);
            b.x = bf2f(v[4]); b.y = bf2f(v[5]); b.z = bf2f(v[6]); b.w = bf2f(v[7]);
            *(vf4*)&feats[r * 8]     = a;
            *(vf4*)&feats[r * 8 + 4] = b;
        }
    }

    __syncthreads();

    vf4* __restrict__ out4 = (vf4*)(out + row0 * OUT_DIM);

    #pragma unroll
    for (int j = 0; j < NITER; ++j) {
        const int r = j * 16 + rbase;
        const vf4 fa = *(const vf4*)&feats[r * 8];
        const vf4 fb = *(const vf4*)&feats[r * 8 + 4];

        vf4 acc = fa.x * Wv[0];
        acc += fa.y * Wv[1];
        acc += fa.z * Wv[2];
        acc += fa.w * Wv[3];
        acc += fb.x * Wv[4];
        acc += fb.y * Wv[5];
        acc += fb.z * Wv[6];
        acc += fb.w * Wv[7];

        __builtin_nontemporal_store(acc, &out4[j * BLK + t]);
    }
}

// ---- fallback: fused fp32 kernel (if ws too small) ----
__global__ __launch_bounds__(BLK) void gshash_f32_kernel(
    const float* __restrict__ codes,
    const float* __restrict__ W,
    const vi4*   __restrict__ map0,
    const vi4*   __restrict__ map1,
    float*       __restrict__ out)
{
    __shared__ float feats[TILE * 8];
    const int t     = threadIdx.x;
    const int col4  = t % 12;
    const int rbase = t / 12;
    const size_t row0 = (size_t)blockIdx.x * TILE;

    vf4 Wv[8];
    #pragma unroll
    for (int k = 0; k < 8; ++k)
        Wv[k] = ((const vf4*)(W + k * OUT_DIM))[col4];

    const float* __restrict__ c1 = codes + LVL0 * 4;

    #pragma unroll
    for (int half = 0; half < 2; ++half) {
        const int r = half * BLK + t;
        if (half == 0 || t < TILE - BLK) {
            const vi4 m0 = __builtin_nontemporal_load(&map0[row0 + r]);
            const vi4 m1 = __builtin_nontemporal_load(&map1[row0 + r]);
            vf4 a, b;
            a.x = codes[m0.x * 4 + 0];
            a.y = codes[m0.y * 4 + 1];
            a.z = codes[m0.z * 4 + 2];
            a.w = codes[m0.w * 4 + 3];
            b.x = c1[m1.x * 4 + 0];
            b.y = c1[m1.y * 4 + 1];
            b.z = c1[m1.z * 4 + 2];
            b.w = c1[m1.w * 4 + 3];
            *(vf4*)&feats[r * 8]     = a;
            *(vf4*)&feats[r * 8 + 4] = b;
        }
    }
    __syncthreads();

    vf4* __restrict__ out4 = (vf4*)(out + row0 * OUT_DIM);
    #pragma unroll
    for (int j = 0; j < NITER; ++j) {
        const int r = j * 16 + rbase;
        const vf4 fa = *(const vf4*)&feats[r * 8];
        const vf4 fb = *(const vf4*)&feats[r * 8 + 4];
        vf4 acc = fa.x * Wv[0];
        acc += fa.y * Wv[1];
        acc += fa.z * Wv[2];
        acc += fa.w * Wv[3];
        acc += fb.x * Wv[4];
        acc += fb.y * Wv[5];
        acc += fb.z * Wv[6];
        acc += fb.w * Wv[7];
        __builtin_nontemporal_store(acc, &out4[j * BLK + t]);
    }
}

extern "C" void kernel_launch(void* const* d_in, const int* in_sizes, int n_in,
                              void* d_out, int out_size, void* d_ws, size_t ws_size,
                              hipStream_t stream) {
    const float* codes = (const float*)d_in[0];
    const float* W     = (const float*)d_in[1];
    const vi4*   map0  = (const vi4*)d_in[2];
    const vi4*   map1  = (const vi4*)d_in[3];
    float*       out   = (float*)d_out;

    const size_t tab_bytes   = (size_t)NCODES * 4 * sizeof(unsigned short);   // 2.62 MB
    const size_t feats_bytes = (size_t)RESO * 8 * sizeof(unsigned short);     // 33.55 MB

    if (ws_size >= tab_bytes + feats_bytes) {
        unsigned short* tab   = (unsigned short*)d_ws;
        vu8*            feats = (vu8*)((char*)d_ws + tab_bytes);              // 16B-aligned
        convert_kernel<<<NCODES / 256, 256, 0, stream>>>(codes, tab);
        gather_kernel<<<RESO / (GBLK * GRPT), GBLK, 0, stream>>>(tab, map0, map1, feats);
        consume_kernel<<<RESO / TILE, BLK, 0, stream>>>(feats, W, out);
    } else {
        gshash_f32_kernel<<<RESO / TILE, BLK, 0, stream>>>(codes, W, map0, map1, out);
    }
}